// Round 9
// baseline (543.706 us; speedup 1.0000x reference)
//
#include <hip/hip_runtime.h>

#define E_CNT 200000
#define N_CNT 50000
#define CS_PARTS 128

typedef __attribute__((ext_vector_type(8))) unsigned short ushort8;
typedef __attribute__((ext_vector_type(4))) unsigned short us4;
typedef __attribute__((ext_vector_type(4))) float f32x4;
typedef __bf16 bf16x8 __attribute__((ext_vector_type(8)));

static __device__ __forceinline__ unsigned short f2bf(float f) {
  unsigned int u = __builtin_bit_cast(unsigned int, f);
  u += 0x7FFFu + ((u >> 16) & 1u);
  return (unsigned short)(u >> 16);
}
static __device__ __forceinline__ float bf2f(unsigned short u) {
  unsigned int x = ((unsigned int)u) << 16;
  return __builtin_bit_cast(float, x);
}

// ---------- fused weight prep ----------
// blocks 0..159: 5 subs x 32 blocks of frag-ready bf16 W conversion
// blocks 160/161: ce = be + g@We_g ; cn = bn + g@Wn_g
__global__ void prep_all(const float* __restrict__ We, const float* __restrict__ be,
                         const float* __restrict__ Wn, const float* __restrict__ bn,
                         const float* __restrict__ g, unsigned short* __restrict__ BpEe,
                         unsigned short* __restrict__ BpPs, unsigned short* __restrict__ BpPr,
                         unsigned short* __restrict__ BpN, float* __restrict__ ce,
                         float* __restrict__ cn) {
  int bid = blockIdx.x;
  if (bid >= 160) {
    int j = threadIdx.x;  // 256
    if (bid == 160) {
      float s = be[j];
      for (int k = 0; k < 128; ++k) s += g[k] * We[(size_t)(768 + k) * 256 + j];
      ce[j] = s;
    } else {
      float s = bn[j];
      for (int k = 0; k < 128; ++k) s += g[k] * Wn[(size_t)(512 + k) * 256 + j];
      cn[j] = s;
    }
    return;
  }
  int sub = bid >> 5;
  const float* W;
  unsigned short* Bp;
  if (sub == 0)      { W = We;           Bp = BpEe; }
  else if (sub == 1) { W = We + 65536;   Bp = BpPs; }
  else if (sub == 2) { W = We + 131072;  Bp = BpPr; }
  else if (sub == 3) { W = Wn;           Bp = BpN; }
  else               { W = Wn + 65536;   Bp = BpN + 65536; }
  int idx = (bid & 31) * 256 + threadIdx.x;  // 0..8191 (KC=8)
  int lane = idx & 63;
  int t = idx >> 6;
  int F = t & 15;
  int kc = t >> 4;
  int col = F * 16 + (lane & 15);
  int kb = kc * 32 + (lane >> 4) * 8;
  ushort8 v;
#pragma unroll
  for (int j = 0; j < 8; ++j) v[j] = f2bf(W[(size_t)(kb + j) * 256 + col]);
  *reinterpret_cast<ushort8*>(Bp + (size_t)idx * 8) = v;
}

// ---------- CSR permutation build ----------
__global__ void hist(const int* __restrict__ recv, int* __restrict__ count) {
  int e = blockIdx.x * blockDim.x + threadIdx.x;
  if (e < E_CNT) atomicAdd(&count[recv[e]], 1);
}

__global__ __launch_bounds__(1024) void scan_build(const int* __restrict__ count,
                                                   int* __restrict__ offs,
                                                   int* __restrict__ cursor) {
  __shared__ int part[1024];
  const int t = threadIdx.x;
  const int CH = 49;  // 1024*49 >= 50000
  const int base = t * CH;
  int s = 0;
  for (int i = 0; i < CH; ++i) {
    int idx = base + i;
    if (idx < N_CNT) s += count[idx];
  }
  part[t] = s;
  __syncthreads();
  for (int d = 1; d < 1024; d <<= 1) {
    int v = (t >= d) ? part[t - d] : 0;
    __syncthreads();
    part[t] += v;
    __syncthreads();
  }
  int run = (t == 0) ? 0 : part[t - 1];
  for (int i = 0; i < CH; ++i) {
    int idx = base + i;
    if (idx < N_CNT) {
      offs[idx] = run;
      cursor[idx] = run;
      run += count[idx];
    }
  }
  if (t == 1023) offs[N_CNT] = run;
}

__global__ void scatter(const int* __restrict__ recv, const int* __restrict__ snd,
                        int* __restrict__ cursor, int* __restrict__ eord,
                        int* __restrict__ sndS, int* __restrict__ rcvS) {
  int e = blockIdx.x * blockDim.x + threadIdx.x;
  if (e < E_CNT) {
    int r = recv[e];
    int pos = atomicAdd(&cursor[r], 1);
    eord[pos] = e;
    rcvS[pos] = r;
    sndS[pos] = snd[e];
  }
}

// ---------- unified GEMM core: 128-row x 256-col tile, 8 waves, wave 64x64 ----------
// MODE 0 (PROJ): two grid halves (nbHalf each) -> Ps / Pr, bf16 slot layout
// MODE 1 (EDGE): A = edges rows in eord (receiver-sorted) order, K=256;
//                v = relu(acc + ce + Ps[sndS] + Pr[rcvS]); nt-store out0[eord];
//                run-combined f32 atomicAdd into agg[rcvS]; fused colsum->partE
// MODE 2 (NODE): A = [agg | nodes] f32, K=512; relu(acc+cn); store; colsum->partN
template <int NSTEPS, int MODE>
__global__ __launch_bounds__(512, 2) void gemm_core(
    const float* __restrict__ A0, const float* __restrict__ A1,
    const unsigned short* __restrict__ Bp, const unsigned short* __restrict__ BpAlt,
    const unsigned short* __restrict__ P1, const unsigned short* __restrict__ P2,
    const float* __restrict__ cvec, const int* __restrict__ eord,
    const int* __restrict__ sndS, const int* __restrict__ rcvS,
    float* __restrict__ outF, unsigned short* __restrict__ outP,
    unsigned short* __restrict__ outPAlt, float* __restrict__ agg,
    float* __restrict__ part, int nbHalf, int M) {
  __shared__ unsigned short lds[2][128 * 64];  // bf16 A tiles, XOR-swizzled

  int bid = blockIdx.x;
  const unsigned short* BpL = Bp;
  unsigned short* outPL = outP;
  if (MODE == 0 && bid >= nbHalf) {
    BpL = BpAlt;
    outPL = outPAlt;
    bid -= nbHalf;
  }

  const int tid = threadIdx.x;
  const int lane = tid & 63;
  const int wave = tid >> 6;  // 0..7
  const int wm = wave >> 2;   // 0..1
  const int wn = wave & 3;    // 0..3
  const int q = lane >> 4;    // 0..3
  const int lr = lane & 15;
  const int row0 = bid * 128;

  // staging: thread stages 16 consecutive floats of one row per K-step
  const int sr = tid >> 2;  // 0..127
  const int sc = tid & 3;   // 16-float chunk
  int er = row0 + sr;
  if (er > M - 1) er = M - 1;
  int srow = er;
  if (MODE == 1) srow = eord[er];  // receiver-sorted gather
  const float* sbase[2];
  sbase[0] = A0 + (size_t)srow * 256;
  sbase[1] = (MODE == 2) ? (A1 + (size_t)srow * 256) : sbase[0];

  const int swz = sr & 7;
  const int wbase = sr * 64;
  const int s0 = ((sc * 2) ^ swz) * 8;
  const int s1 = ((sc * 2 + 1) ^ swz) * 8;

  f32x4 acc[4][4] = {};

  // ---- prologue: stage step 0 ----
  {
    const float4* p4 = reinterpret_cast<const float4*>(sbase[0] + sc * 16);
    float fv[16];
    *reinterpret_cast<float4*>(&fv[0]) = p4[0];
    *reinterpret_cast<float4*>(&fv[4]) = p4[1];
    *reinterpret_cast<float4*>(&fv[8]) = p4[2];
    *reinterpret_cast<float4*>(&fv[12]) = p4[3];
    ushort8 w0, w1;
#pragma unroll
    for (int j = 0; j < 8; ++j) {
      w0[j] = f2bf(fv[j]);
      w1[j] = f2bf(fv[8 + j]);
    }
    *reinterpret_cast<ushort8*>(&lds[0][wbase + s0]) = w0;
    *reinterpret_cast<ushort8*>(&lds[0][wbase + s1]) = w1;
  }
  __syncthreads();

#pragma unroll
  for (int ks = 0; ks < NSTEPS; ++ks) {
    const int cc = ks & 1;

    // B-frags for this step (L2-hot)
    bf16x8 bfr[2][4];
#pragma unroll
    for (int kk = 0; kk < 2; ++kk) {
      const int kc32 = ks * 2 + kk;
#pragma unroll
      for (int fn = 0; fn < 4; ++fn) {
        const int F = wn * 4 + fn;
        bfr[kk][fn] = __builtin_bit_cast(
            bf16x8, *reinterpret_cast<const ushort8*>(
                        BpL + ((size_t)(kc32 * 16 + F) * 64 + lane) * 8));
      }
    }

    // next-step A loads to regs
    float4 nf0, nf1, nf2, nf3;
    if (ks + 1 < NSTEPS) {
      const float4* p4 = reinterpret_cast<const float4*>(
          sbase[(ks + 1) >> 2] + ((ks + 1) & 3) * 64 + sc * 16);
      nf0 = p4[0];
      nf1 = p4[1];
      nf2 = p4[2];
      nf3 = p4[3];
    }

    // MFMA on lds[cc]
#pragma unroll
    for (int kk = 0; kk < 2; ++kk) {
      bf16x8 a[4];
#pragma unroll
      for (int fm = 0; fm < 4; ++fm) {
        int r = wm * 64 + fm * 16 + lr;
        int slot = (kk * 4 + q) ^ (r & 7);
        a[fm] = __builtin_bit_cast(
            bf16x8, *reinterpret_cast<const ushort8*>(&lds[cc][r * 64 + slot * 8]));
      }
#pragma unroll
      for (int fm = 0; fm < 4; ++fm)
#pragma unroll
        for (int fn = 0; fn < 4; ++fn)
          acc[fm][fn] = __builtin_amdgcn_mfma_f32_16x16x32_bf16(
              a[fm], bfr[kk][fn], acc[fm][fn], 0, 0, 0);
    }

    // convert + write next tile
    if (ks + 1 < NSTEPS) {
      float fv[16];
      *reinterpret_cast<float4*>(&fv[0]) = nf0;
      *reinterpret_cast<float4*>(&fv[4]) = nf1;
      *reinterpret_cast<float4*>(&fv[8]) = nf2;
      *reinterpret_cast<float4*>(&fv[12]) = nf3;
      ushort8 w0, w1;
#pragma unroll
      for (int j = 0; j < 8; ++j) {
        w0[j] = f2bf(fv[j]);
        w1[j] = f2bf(fv[8 + j]);
      }
      *reinterpret_cast<ushort8*>(&lds[cc ^ 1][wbase + s0]) = w0;
      *reinterpret_cast<ushort8*>(&lds[cc ^ 1][wbase + s1]) = w1;
      __syncthreads();
    }
  }

  // ---- epilogue ----
  // D mapping: col = lane&15 (=lr), row = q*4 + i
  float bcol[4];
  if (MODE != 0) {
#pragma unroll
    for (int fn = 0; fn < 4; ++fn) bcol[fn] = cvec[wn * 64 + fn * 16 + lr];
  }
  float cs[4] = {0.f, 0.f, 0.f, 0.f};  // per-thread column-sum partials

#pragma unroll
  for (int fm = 0; fm < 4; ++fm) {
    int rb = row0 + wm * 64 + fm * 16 + q * 4;
    if (MODE == 0) {
#pragma unroll
      for (int i = 0; i < 4; ++i) {
        int gr = rb + i;
        if (gr < M) {
          us4 pv;
#pragma unroll
          for (int fn = 0; fn < 4; ++fn) pv[fn] = f2bf(acc[fm][fn][i]);
          *reinterpret_cast<us4*>(outPL + (size_t)gr * 256 + wn * 64 + lr * 4) = pv;
        }
      }
    } else if (MODE == 1) {
      // rows rb..rb+3 are consecutive receiver-sorted slots: combine runs
      float runv[4];
      int runr = -1;
#pragma unroll
      for (int i = 0; i < 4; ++i) {
        int gr = rb + i;
        if (gr < M) {
          int e = eord[gr];
          int snd = sndS[gr];
          int rcv = rcvS[gr];
          us4 ps = *reinterpret_cast<const us4*>(P1 + (size_t)snd * 256 + wn * 64 + lr * 4);
          us4 pr = *reinterpret_cast<const us4*>(P2 + (size_t)rcv * 256 + wn * 64 + lr * 4);
          float v[4];
#pragma unroll
          for (int fn = 0; fn < 4; ++fn) {
            v[fn] = fmaxf(acc[fm][fn][i] + bcol[fn] + bf2f(ps[fn]) + bf2f(pr[fn]), 0.0f);
            cs[fn] += v[fn];
            __builtin_nontemporal_store(
                v[fn], &outF[(size_t)e * 256 + wn * 64 + fn * 16 + lr]);
          }
          if (rcv == runr) {
#pragma unroll
            for (int fn = 0; fn < 4; ++fn) runv[fn] += v[fn];
          } else {
            if (runr >= 0) {
#pragma unroll
              for (int fn = 0; fn < 4; ++fn)
                atomicAdd(agg + (size_t)runr * 256 + wn * 64 + fn * 16 + lr, runv[fn]);
            }
            runr = rcv;
#pragma unroll
            for (int fn = 0; fn < 4; ++fn) runv[fn] = v[fn];
          }
        }
      }
      if (runr >= 0) {
#pragma unroll
        for (int fn = 0; fn < 4; ++fn)
          atomicAdd(agg + (size_t)runr * 256 + wn * 64 + fn * 16 + lr, runv[fn]);
      }
    } else {
#pragma unroll
      for (int i = 0; i < 4; ++i) {
        int gr = rb + i;
        if (gr < M) {
#pragma unroll
          for (int fn = 0; fn < 4; ++fn) {
            float v = fmaxf(acc[fm][fn][i] + bcol[fn], 0.0f);
            cs[fn] += v;
            outF[(size_t)gr * 256 + wn * 64 + fn * 16 + lr] = v;
          }
        }
      }
    }
  }

  // ---- fused column sum (MODE 1/2): LDS reduce -> partial slot ----
  if (MODE != 0) {
    float* csum = reinterpret_cast<float*>(&lds[0][0]);  // 256 f32 (lds[0] is dead)
    __syncthreads();
    if (tid < 256) csum[tid] = 0.f;
    __syncthreads();
#pragma unroll
    for (int fn = 0; fn < 4; ++fn) atomicAdd(&csum[wn * 64 + fn * 16 + lr], cs[fn]);
    __syncthreads();
    if (tid < 256)
      atomicAdd(&part[(size_t)(blockIdx.x & (CS_PARTS - 1)) * 256 + tid], csum[tid]);
  }
}

// sum the CS_PARTS partials
__global__ void colsum_p2(const float* __restrict__ part, float* __restrict__ out) {
  const int c = threadIdx.x;  // 256
  float s = 0.f;
  for (int p = 0; p < CS_PARTS; ++p) s += part[(size_t)p * 256 + c];
  out[c] = s;
}

// new_globals = relu([esum | nsum | globals] @ Wg + bg), fp32
__global__ void global_mlp(const float* __restrict__ esum, const float* __restrict__ nsum,
                           const float* __restrict__ gl, const float* __restrict__ Wg,
                           const float* __restrict__ bg, float* __restrict__ out2) {
  __shared__ float red[512];
  int g = threadIdx.x & 127;
  int kg = threadIdx.x >> 7;
  float acc = 0.f;
  for (int k = kg; k < 640; k += 4) {
    float x = (k < 256) ? esum[k] : (k < 512 ? nsum[k - 256] : gl[k - 512]);
    acc += x * Wg[(size_t)k * 128 + g];
  }
  red[threadIdx.x] = acc;
  __syncthreads();
  if (kg == 0) {
    float r = red[g] + red[128 + g] + red[256 + g] + red[384 + g] + bg[g];
    out2[g] = fmaxf(r, 0.f);
  }
}

extern "C" void kernel_launch(void* const* d_in, const int* in_sizes, int n_in,
                              void* d_out, int out_size, void* d_ws, size_t ws_size,
                              hipStream_t stream) {
  const float* nodes = (const float*)d_in[0];
  const float* edges = (const float*)d_in[1];
  const float* gl = (const float*)d_in[2];
  const int* senders = (const int*)d_in[3];
  const int* receivers = (const int*)d_in[4];
  const float* We = (const float*)d_in[5];
  const float* be = (const float*)d_in[6];
  const float* Wn = (const float*)d_in[7];
  const float* bn = (const float*)d_in[8];
  const float* Wg = (const float*)d_in[9];
  const float* bg = (const float*)d_in[10];

  float* out0 = (float*)d_out;               // new_edges [200000,256]
  float* out1 = out0 + (size_t)E_CNT * 256;  // new_nodes [50000,256]
  float* out2 = out1 + (size_t)N_CNT * 256;  // new_globals [128]

  // agg (f32) lives in out1's slot during the edge phase; the node kernel
  // reads agg[row] and overwrites out1[row] for the same rows only.
  float* agg = out1;

  char* ws = (char*)d_ws;
  size_t o = 0;
  int* count = (int*)(ws + o);                      o += 200704;
  float* partE = (float*)(ws + o);                  o += CS_PARTS * 256 * 4;
  float* partN = (float*)(ws + o);                  o += CS_PARTS * 256 * 4;
  size_t zeroBytes = o;  // count+partE+partN zeroed together
  int* offs = (int*)(ws + o);                       o += 200704;
  int* cursor = (int*)(ws + o);                     o += 200704;
  int* eord = (int*)(ws + o);                       o += 800000;
  int* sndS = (int*)(ws + o);                       o += 800000;
  int* rcvS = (int*)(ws + o);                       o += 800000;
  unsigned short* Ps = (unsigned short*)(ws + o);   o += (size_t)N_CNT * 256 * 2;
  unsigned short* Pr = (unsigned short*)(ws + o);   o += (size_t)N_CNT * 256 * 2;
  unsigned short* BpEe = (unsigned short*)(ws + o); o += 131072;
  unsigned short* BpPs = (unsigned short*)(ws + o); o += 131072;
  unsigned short* BpPr = (unsigned short*)(ws + o); o += 131072;
  unsigned short* BpN = (unsigned short*)(ws + o);  o += 262144;
  float* ce = (float*)(ws + o);                     o += 1024;
  float* cn = (float*)(ws + o);                     o += 1024;
  float* esum = (float*)(ws + o);                   o += 1024;
  float* nsum = (float*)(ws + o);                   o += 1024;

  hipMemsetAsync(ws, 0, zeroBytes, stream);
  hipMemsetAsync(agg, 0, (size_t)N_CNT * 256 * 4, stream);

  prep_all<<<162, 256, 0, stream>>>(We, be, Wn, bn, gl, BpEe, BpPs, BpPr, BpN, ce, cn);

  hist<<<(E_CNT + 255) / 256, 256, 0, stream>>>(receivers, count);

  // both projections in one dispatch: Ps = nodes@We_s, Pr = nodes@We_r
  const int nbN = (N_CNT + 127) / 128;  // 391
  gemm_core<4, 0><<<2 * nbN, 512, 0, stream>>>(
      nodes, nullptr, BpPs, BpPr, nullptr, nullptr, nullptr, nullptr, nullptr,
      nullptr, nullptr, Ps, Pr, nullptr, nullptr, nbN, N_CNT);

  scan_build<<<1, 1024, 0, stream>>>(count, offs, cursor);
  scatter<<<(E_CNT + 255) / 256, 256, 0, stream>>>(receivers, senders, cursor,
                                                   eord, sndS, rcvS);

  // edge: receiver-sorted; relu(edges@We_e + Ps[s] + Pr[r] + ce);
  // run-combined f32 atomic segment-sum into agg; fused esum partials
  gemm_core<4, 1><<<(E_CNT + 127) / 128, 512, 0, stream>>>(
      edges, nullptr, BpEe, nullptr, Ps, Pr, ce, eord, sndS, rcvS, out0,
      nullptr, nullptr, agg, partE, 1 << 30, E_CNT);

  colsum_p2<<<1, 256, 0, stream>>>(partE, esum);

  // node: relu(agg@Wn_e + nodes@Wn_v + cn)  (K=512); fused nsum partials
  gemm_core<8, 2><<<nbN, 512, 0, stream>>>(
      agg, nodes, BpN, nullptr, nullptr, nullptr, cn, nullptr, nullptr, nullptr,
      out1, nullptr, nullptr, nullptr, partN, 1 << 30, N_CNT);

  colsum_p2<<<1, 256, 0, stream>>>(partN, nsum);

  global_mlp<<<1, 512, 0, stream>>>(esum, nsum, gl, Wg, bg, out2);
}